// Round 4
// baseline (154.973 us; speedup 1.0000x reference)
//
#include <hip/hip_runtime.h>

constexpr int C_ = 1000;
constexpr int A_ = 512;
constexpr int N_ = 65536;
constexpr int CA_ = C_ * A_;
constexpr float ONE_MINUS_M = 0.2f;   // 1 - MOMENTUM

constexpr int NBLK = 250;             // <= 256 CUs -> all blocks co-resident (grid barrier safe)
constexpr int TPB  = 512;             // 8 waves
constexpr int CPB  = 4;               // classes per block (250*4 = 1000)

// Device-scope grid barrier among NBLK co-resident blocks.
// Release: flush this block's stores to the coherent point before arrival.
// Acquire: invalidate stale L2/L1 lines before reading other blocks' data.
__device__ inline void grid_barrier(int* ctr) {
    __syncthreads();
    if (threadIdx.x == 0) {
        __threadfence();   // release side (wbl2 on gfx950)
        __hip_atomic_fetch_add(ctr, 1, __ATOMIC_RELEASE, __HIP_MEMORY_SCOPE_AGENT);
        long spin = 0;
        while (__hip_atomic_load(ctr, __ATOMIC_ACQUIRE, __HIP_MEMORY_SCOPE_AGENT) < NBLK) {
            __builtin_amdgcn_s_sleep(2);
            if (++spin > (1L << 27)) break;   // safety valve; structurally unreachable
        }
    }
    __syncthreads();
    __threadfence();       // acquire side for all threads (buffer_inv)
}

__global__ __launch_bounds__(TPB, 4) void fused_kernel(
    const float* __restrict__ feat, const int* __restrict__ labels,
    const float* __restrict__ cov, const float* __restrict__ mean,
    const float* __restrict__ amount, float* __restrict__ out,
    int* cnt, int* perm, int* ctr)
{
    __shared__ int   sbase[1008];          // exclusive scan of cnt; sbase[1000] = N
    __shared__ int   sscan[TPB];
    __shared__ float lred[CPB == 4 ? 4 * 128 * 9 : 1];  // stride 9: conflict-free

    const int tid = threadIdx.x;
    const int gid = blockIdx.x * TPB + tid;

    // ---- Phase 1: histogram + per-row rank in one atomic pass ----
    int lab = -1, rank = 0;
    if (gid < N_) {
        lab  = labels[gid];
        rank = atomicAdd(&cnt[lab], 1);    // device-scope
    }
    grid_barrier(&ctr[0]);

    // ---- Phase 2: redundant per-block exclusive scan of cnt[0..999] ----
    int v0 = 0, v1 = 0;
    if (tid < 500) { v0 = cnt[2 * tid]; v1 = cnt[2 * tid + 1]; }
    const int pairsum = v0 + v1;
    sscan[tid] = pairsum;
    __syncthreads();
    for (int off = 1; off < TPB; off <<= 1) {
        const int x = (tid >= off) ? sscan[tid - off] : 0;
        __syncthreads();
        sscan[tid] += x;
        __syncthreads();
    }
    if (tid < 500) {
        const int excl = sscan[tid] - pairsum;   // exclusive over pairs
        sbase[2 * tid]     = excl;
        sbase[2 * tid + 1] = excl + v0;
    }
    if (tid == 0) sbase[1000] = sscan[TPB - 1];  // = N_
    __syncthreads();

    // ---- Phase 3: scatter row ids into class buckets ----
    if (gid < N_) perm[sbase[lab] + rank] = gid;
    grid_barrier(&ctr[1]);

    // ---- Phase 4: per-class gather-reduce + fused EMA finalize ----
    const int g  = tid >> 7;      // row group 0..3
    const int ct = tid & 127;     // col thread
    const int cb = ct * 4;        // column base (float4)

    for (int j = 0; j < CPB; ++j) {
        const int c    = blockIdx.x * CPB + j;
        const int b0   = sbase[c];
        const int cntc = sbase[c + 1] - b0;

        float4 s = {0.f, 0.f, 0.f, 0.f};
        float4 q = {0.f, 0.f, 0.f, 0.f};

        int r = g;
        for (; r + 4 < cntc; r += 8) {           // 2-deep: rows r and r+4
            const int r0 = perm[b0 + r];
            const int r1 = perm[b0 + r + 4];
            const float4 a = *reinterpret_cast<const float4*>(feat + (size_t)r0 * A_ + cb);
            const float4 b = *reinterpret_cast<const float4*>(feat + (size_t)r1 * A_ + cb);
            s.x += a.x; s.y += a.y; s.z += a.z; s.w += a.w;
            q.x = fmaf(a.x, a.x, q.x); q.y = fmaf(a.y, a.y, q.y);
            q.z = fmaf(a.z, a.z, q.z); q.w = fmaf(a.w, a.w, q.w);
            s.x += b.x; s.y += b.y; s.z += b.z; s.w += b.w;
            q.x = fmaf(b.x, b.x, q.x); q.y = fmaf(b.y, b.y, q.y);
            q.z = fmaf(b.z, b.z, q.z); q.w = fmaf(b.w, b.w, q.w);
        }
        for (; r < cntc; r += 4) {               // tail rows of this group
            const int r0 = perm[b0 + r];
            const float4 a = *reinterpret_cast<const float4*>(feat + (size_t)r0 * A_ + cb);
            s.x += a.x; s.y += a.y; s.z += a.z; s.w += a.w;
            q.x = fmaf(a.x, a.x, q.x); q.y = fmaf(a.y, a.y, q.y);
            q.z = fmaf(a.z, a.z, q.z); q.w = fmaf(a.w, a.w, q.w);
        }

        // combine 4 groups via LDS (stride 9 words -> conflict-free)
        float* myred = &lred[(g * 128 + ct) * 9];
        myred[0] = s.x; myred[1] = s.y; myred[2] = s.z; myred[3] = s.w;
        myred[4] = q.x; myred[5] = q.y; myred[6] = q.z; myred[7] = q.w;
        __syncthreads();
        if (g == 0) {
            #pragma unroll
            for (int gg = 1; gg < 4; ++gg) {
                const float* p = &lred[(gg * 128 + ct) * 9];
                s.x += p[0]; s.y += p[1]; s.z += p[2]; s.w += p[3];
                q.x += p[4]; q.y += p[5]; q.z += p[6]; q.w += p[7];
            }
            const float cntf = (float)cntc;
            const float safe = (cntc == 0) ? 1.f : cntf;
            const float inv  = 1.f / safe;
            float4 ave, var;
            ave.x = s.x * inv; ave.y = s.y * inv; ave.z = s.z * inv; ave.w = s.w * inv;
            var.x = fmaxf(q.x * inv - ave.x * ave.x, 0.f);
            var.y = fmaxf(q.y * inv - ave.y * ave.y, 0.f);
            var.z = fmaxf(q.z * inv - ave.z * ave.z, 0.f);
            var.w = fmaxf(q.w * inv - ave.w * ave.w, 0.f);

            const float amt   = amount[c];
            const float den   = cntf + amt;
            const float w_raw = (den > 0.f) ? (cntf / den) : 0.f;
            const float w     = (w_raw > 0.f) ? fmaxf(w_raw, ONE_MINUS_M) : 0.f;
            const float omw   = 1.f - w;

            const int idx = c * A_ + cb;
            const float4 m  = *reinterpret_cast<const float4*>(mean + idx);
            const float4 cv = *reinterpret_cast<const float4*>(cov + idx);
            const float dx = m.x - ave.x, dy = m.y - ave.y,
                        dz = m.z - ave.z, dw = m.w - ave.w;
            float4 oc, om;
            oc.x = cv.x * omw + var.x * w + w * omw * dx * dx;
            oc.y = cv.y * omw + var.y * w + w * omw * dy * dy;
            oc.z = cv.z * omw + var.z * w + w * omw * dz * dz;
            oc.w = cv.w * omw + var.w * w + w * omw * dw * dw;
            om.x = m.x * omw + ave.x * w;
            om.y = m.y * omw + ave.y * w;
            om.z = m.z * omw + ave.z * w;
            om.w = m.w * omw + ave.w * w;
            *reinterpret_cast<float4*>(out + idx)       = oc;
            *reinterpret_cast<float4*>(out + CA_ + idx) = om;
            if (ct == 0) out[2 * CA_ + c] = amt + cntf;
        }
        __syncthreads();   // lred reused next class
    }
}

extern "C" void kernel_launch(void* const* d_in, const int* in_sizes, int n_in,
                              void* d_out, int out_size, void* d_ws, size_t ws_size,
                              hipStream_t stream)
{
    const float* feat   = (const float*)d_in[0];
    const int*   labels = (const int*)  d_in[1];
    const float* cov    = (const float*)d_in[2];
    const float* mean   = (const float*)d_in[3];
    const float* amount = (const float*)d_in[4];
    float* out = (float*)d_out;

    // ws layout (ints): cnt[1024] | ctr[16] | perm[65536]
    int* cnt  = (int*)d_ws;
    int* ctr  = cnt + 1024;
    int* perm = cnt + 1040;

    hipMemsetAsync(d_ws, 0, (1024 + 16) * sizeof(int), stream);
    fused_kernel<<<NBLK, TPB, 0, stream>>>(feat, labels, cov, mean, amount,
                                           out, cnt, perm, ctr);
}

// Round 5
// 37.427 us; speedup vs baseline: 4.1407x; 4.1407x over previous
//
#include <hip/hip_runtime.h>

constexpr int C_ = 1000;
constexpr int A_ = 512;
constexpr int N_ = 65536;
constexpr int CA_ = C_ * A_;
constexpr float ONE_MINUS_M = 0.2f;   // 1 - MOMENTUM

constexpr int TPB  = 512;             // 4 row-groups x 128 col-threads
constexpr int MAXR = 512;             // rows-per-class bound (mean 65.5; 50+ sigma headroom)

// One block per class. Phase 1: filter labels (L2-resident) for rows of this
// class into LDS. Phase 2: coalesced float4 gather-reduce of those rows,
// 4 rows in flight per thread. Phase 3: cross-group LDS combine + fused EMA
// finalize. No global atomics, no workspace, no inter-block dependencies.
__global__ __launch_bounds__(TPB, 8) void fused_kernel(
    const float* __restrict__ feat, const int* __restrict__ labels,
    const float* __restrict__ cov, const float* __restrict__ mean,
    const float* __restrict__ amount, float* __restrict__ out)
{
    __shared__ int   lrows[MAXR];
    __shared__ int   lcnt;
    __shared__ float lred[3 * 128 * 9];   // groups 1..3 partials, stride 9 (conflict-free)

    const int c   = blockIdx.x;
    const int tid = threadIdx.x;
    if (tid == 0) lcnt = 0;
    __syncthreads();

    // ---- Phase 1: redundant label filter (256 KB from L2/L3) ----
    const int4* lab4 = reinterpret_cast<const int4*>(labels);
    for (int it = tid; it < N_ / 4; it += TPB) {
        const int4 L  = lab4[it];
        const int  r0 = it * 4;
        if (L.x == c) lrows[atomicAdd(&lcnt, 1)] = r0;
        if (L.y == c) lrows[atomicAdd(&lcnt, 1)] = r0 + 1;
        if (L.z == c) lrows[atomicAdd(&lcnt, 1)] = r0 + 2;
        if (L.w == c) lrows[atomicAdd(&lcnt, 1)] = r0 + 3;
    }
    __syncthreads();
    const int cntc = lcnt;

    // ---- Phase 2: gather-reduce ----
    const int g  = tid >> 7;      // row group 0..3
    const int ct = tid & 127;     // col thread
    const int cb = ct * 4;        // column base (float4): cols 0..511

    float4 s = {0.f, 0.f, 0.f, 0.f};
    float4 q = {0.f, 0.f, 0.f, 0.f};

    int r = g;                    // group g owns rows g, g+4, g+8, ...
    for (; r + 12 < cntc; r += 16) {        // 4 rows in flight
        int ri[4];
        #pragma unroll
        for (int u = 0; u < 4; ++u) ri[u] = lrows[r + 4 * u];
        float4 v[4];
        #pragma unroll
        for (int u = 0; u < 4; ++u)
            v[u] = *reinterpret_cast<const float4*>(feat + (size_t)ri[u] * A_ + cb);
        #pragma unroll
        for (int u = 0; u < 4; ++u) {
            s.x += v[u].x; s.y += v[u].y; s.z += v[u].z; s.w += v[u].w;
            q.x = fmaf(v[u].x, v[u].x, q.x);
            q.y = fmaf(v[u].y, v[u].y, q.y);
            q.z = fmaf(v[u].z, v[u].z, q.z);
            q.w = fmaf(v[u].w, v[u].w, q.w);
        }
    }
    for (; r < cntc; r += 4) {              // tail
        const int rr = lrows[r];
        const float4 v = *reinterpret_cast<const float4*>(feat + (size_t)rr * A_ + cb);
        s.x += v.x; s.y += v.y; s.z += v.z; s.w += v.w;
        q.x = fmaf(v.x, v.x, q.x); q.y = fmaf(v.y, v.y, q.y);
        q.z = fmaf(v.z, v.z, q.z); q.w = fmaf(v.w, v.w, q.w);
    }

    // ---- Phase 3: cross-group combine + fused finalize ----
    if (g > 0) {
        float* p = &lred[((g - 1) * 128 + ct) * 9];
        p[0] = s.x; p[1] = s.y; p[2] = s.z; p[3] = s.w;
        p[4] = q.x; p[5] = q.y; p[6] = q.z; p[7] = q.w;
    }
    __syncthreads();
    if (g == 0) {
        #pragma unroll
        for (int gg = 0; gg < 3; ++gg) {
            const float* p = &lred[(gg * 128 + ct) * 9];
            s.x += p[0]; s.y += p[1]; s.z += p[2]; s.w += p[3];
            q.x += p[4]; q.y += p[5]; q.z += p[6]; q.w += p[7];
        }
        const float cntf = (float)cntc;
        const float safe = (cntc == 0) ? 1.f : cntf;
        const float inv  = 1.f / safe;
        float4 ave, var;
        ave.x = s.x * inv; ave.y = s.y * inv; ave.z = s.z * inv; ave.w = s.w * inv;
        var.x = fmaxf(q.x * inv - ave.x * ave.x, 0.f);
        var.y = fmaxf(q.y * inv - ave.y * ave.y, 0.f);
        var.z = fmaxf(q.z * inv - ave.z * ave.z, 0.f);
        var.w = fmaxf(q.w * inv - ave.w * ave.w, 0.f);

        const float amt   = amount[c];
        const float den   = cntf + amt;
        const float w_raw = (den > 0.f) ? (cntf / den) : 0.f;
        const float w     = (w_raw > 0.f) ? fmaxf(w_raw, ONE_MINUS_M) : 0.f;
        const float omw   = 1.f - w;

        const int idx = c * A_ + cb;
        const float4 m  = *reinterpret_cast<const float4*>(mean + idx);
        const float4 cv = *reinterpret_cast<const float4*>(cov + idx);
        const float dx = m.x - ave.x, dy = m.y - ave.y,
                    dz = m.z - ave.z, dw = m.w - ave.w;
        float4 oc, om;
        oc.x = cv.x * omw + var.x * w + w * omw * dx * dx;
        oc.y = cv.y * omw + var.y * w + w * omw * dy * dy;
        oc.z = cv.z * omw + var.z * w + w * omw * dz * dz;
        oc.w = cv.w * omw + var.w * w + w * omw * dw * dw;
        om.x = m.x * omw + ave.x * w;
        om.y = m.y * omw + ave.y * w;
        om.z = m.z * omw + ave.z * w;
        om.w = m.w * omw + ave.w * w;
        *reinterpret_cast<float4*>(out + idx)       = oc;
        *reinterpret_cast<float4*>(out + CA_ + idx) = om;
        if (ct == 0) out[2 * CA_ + c] = amt + cntf;
    }
}

extern "C" void kernel_launch(void* const* d_in, const int* in_sizes, int n_in,
                              void* d_out, int out_size, void* d_ws, size_t ws_size,
                              hipStream_t stream)
{
    const float* feat   = (const float*)d_in[0];
    const int*   labels = (const int*)  d_in[1];
    const float* cov    = (const float*)d_in[2];
    const float* mean   = (const float*)d_in[3];
    const float* amount = (const float*)d_in[4];
    float* out = (float*)d_out;

    fused_kernel<<<C_, TPB, 0, stream>>>(feat, labels, cov, mean, amount, out);
}

// Round 6
// 29.960 us; speedup vs baseline: 5.1727x; 1.2492x over previous
//
#include <hip/hip_runtime.h>

constexpr int C_ = 1000;
constexpr int A_ = 512;
constexpr int N_ = 65536;
constexpr int CA_ = C_ * A_;
constexpr float ONE_MINUS_M = 0.2f;   // 1 - MOMENTUM

constexpr int TPB    = 512;           // 4 row-groups x 128 col-threads
constexpr int NCHUNK = 8;
constexpr int RPC    = N_ / NCHUNK;   // 8192 rows per chunk
constexpr int I4PT   = RPC / 4 / TPB; // 4 int4 label loads per thread per chunk
constexpr int CAP    = 512;           // per-chunk per-class row bound (mean ~8)

// One block per class. Software-pipelined: while gathering chunk k's rows
// (HBM-heavy), the labels of chunk k+1 are already in flight from L2.
__global__ __launch_bounds__(TPB, 8) void fused_kernel(
    const float* __restrict__ feat, const int* __restrict__ labels,
    const float* __restrict__ cov, const float* __restrict__ mean,
    const float* __restrict__ amount, float* __restrict__ out)
{
    __shared__ int   lrows[2][CAP];
    __shared__ int   lcnt[2];
    __shared__ float lred[3 * 128 * 9];   // groups 1..3 partials, stride 9

    const int c   = blockIdx.x;
    const int tid = threadIdx.x;
    if (tid < 2) lcnt[tid] = 0;
    __syncthreads();

    const int4* lab4 = reinterpret_cast<const int4*>(labels);

    const int g  = tid >> 7;      // row group 0..3
    const int ct = tid & 127;     // col thread
    const int cb = ct * 4;        // column base (float4)

    float4 s = {0.f, 0.f, 0.f, 0.f};
    float4 q = {0.f, 0.f, 0.f, 0.f};
    int cnt_total = 0;

    // ---- prologue: filter chunk 0 into list 0 ----
    int4 L[I4PT];
    #pragma unroll
    for (int u = 0; u < I4PT; ++u) L[u] = lab4[u * TPB + tid];
    #pragma unroll
    for (int u = 0; u < I4PT; ++u) {
        const int r0 = (u * TPB + tid) * 4;
        if (L[u].x == c) lrows[0][atomicAdd(&lcnt[0], 1)] = r0;
        if (L[u].y == c) lrows[0][atomicAdd(&lcnt[0], 1)] = r0 + 1;
        if (L[u].z == c) lrows[0][atomicAdd(&lcnt[0], 1)] = r0 + 2;
        if (L[u].w == c) lrows[0][atomicAdd(&lcnt[0], 1)] = r0 + 3;
    }
    __syncthreads();

    for (int k = 0; k < NCHUNK; ++k) {
        const int b     = k & 1;
        const int cnt_b = min(lcnt[b], CAP);   // list b is complete (sync'd)
        cnt_total += cnt_b;

        // (a) issue next chunk's label loads — in flight during the gather
        if (k < NCHUNK - 1) {
            #pragma unroll
            for (int u = 0; u < I4PT; ++u)
                L[u] = lab4[(k + 1) * (RPC / 4) + u * TPB + tid];
        }

        // (b) gather this chunk's rows (group g owns rows g, g+4, ...)
        int r = g;
        for (; r + 4 < cnt_b; r += 8) {        // 2 rows in flight
            const int r0 = lrows[b][r];
            const int r1 = lrows[b][r + 4];
            const float4 a0 = *reinterpret_cast<const float4*>(feat + (size_t)r0 * A_ + cb);
            const float4 a1 = *reinterpret_cast<const float4*>(feat + (size_t)r1 * A_ + cb);
            s.x += a0.x; s.y += a0.y; s.z += a0.z; s.w += a0.w;
            q.x = fmaf(a0.x, a0.x, q.x); q.y = fmaf(a0.y, a0.y, q.y);
            q.z = fmaf(a0.z, a0.z, q.z); q.w = fmaf(a0.w, a0.w, q.w);
            s.x += a1.x; s.y += a1.y; s.z += a1.z; s.w += a1.w;
            q.x = fmaf(a1.x, a1.x, q.x); q.y = fmaf(a1.y, a1.y, q.y);
            q.z = fmaf(a1.z, a1.z, q.z); q.w = fmaf(a1.w, a1.w, q.w);
        }
        for (; r < cnt_b; r += 4) {
            const int r0 = lrows[b][r];
            const float4 a0 = *reinterpret_cast<const float4*>(feat + (size_t)r0 * A_ + cb);
            s.x += a0.x; s.y += a0.y; s.z += a0.z; s.w += a0.w;
            q.x = fmaf(a0.x, a0.x, q.x); q.y = fmaf(a0.y, a0.y, q.y);
            q.z = fmaf(a0.z, a0.z, q.z); q.w = fmaf(a0.w, a0.w, q.w);
        }

        if (tid == 0) lcnt[b] = 0;             // ready for reuse at k+2

        // (c) append next chunk's matches to the other list
        if (k < NCHUNK - 1) {
            const int nb = b ^ 1;
            #pragma unroll
            for (int u = 0; u < I4PT; ++u) {
                const int r0 = ((k + 1) * (RPC / 4) + u * TPB + tid) * 4;
                if (L[u].x == c) lrows[nb][atomicAdd(&lcnt[nb], 1)] = r0;
                if (L[u].y == c) lrows[nb][atomicAdd(&lcnt[nb], 1)] = r0 + 1;
                if (L[u].z == c) lrows[nb][atomicAdd(&lcnt[nb], 1)] = r0 + 2;
                if (L[u].w == c) lrows[nb][atomicAdd(&lcnt[nb], 1)] = r0 + 3;
            }
        }
        __syncthreads();
    }

    // ---- cross-group combine + fused finalize ----
    if (g > 0) {
        float* p = &lred[((g - 1) * 128 + ct) * 9];
        p[0] = s.x; p[1] = s.y; p[2] = s.z; p[3] = s.w;
        p[4] = q.x; p[5] = q.y; p[6] = q.z; p[7] = q.w;
    }
    __syncthreads();
    if (g == 0) {
        #pragma unroll
        for (int gg = 0; gg < 3; ++gg) {
            const float* p = &lred[(gg * 128 + ct) * 9];
            s.x += p[0]; s.y += p[1]; s.z += p[2]; s.w += p[3];
            q.x += p[4]; q.y += p[5]; q.z += p[6]; q.w += p[7];
        }
        const int   cntc = cnt_total;
        const float cntf = (float)cntc;
        const float safe = (cntc == 0) ? 1.f : cntf;
        const float inv  = 1.f / safe;
        float4 ave, var;
        ave.x = s.x * inv; ave.y = s.y * inv; ave.z = s.z * inv; ave.w = s.w * inv;
        var.x = fmaxf(q.x * inv - ave.x * ave.x, 0.f);
        var.y = fmaxf(q.y * inv - ave.y * ave.y, 0.f);
        var.z = fmaxf(q.z * inv - ave.z * ave.z, 0.f);
        var.w = fmaxf(q.w * inv - ave.w * ave.w, 0.f);

        const float amt   = amount[c];
        const float den   = cntf + amt;
        const float w_raw = (den > 0.f) ? (cntf / den) : 0.f;
        const float w     = (w_raw > 0.f) ? fmaxf(w_raw, ONE_MINUS_M) : 0.f;
        const float omw   = 1.f - w;

        const int idx = c * A_ + cb;
        const float4 m  = *reinterpret_cast<const float4*>(mean + idx);
        const float4 cv = *reinterpret_cast<const float4*>(cov + idx);
        const float dx = m.x - ave.x, dy = m.y - ave.y,
                    dz = m.z - ave.z, dw = m.w - ave.w;
        float4 oc, om;
        oc.x = cv.x * omw + var.x * w + w * omw * dx * dx;
        oc.y = cv.y * omw + var.y * w + w * omw * dy * dy;
        oc.z = cv.z * omw + var.z * w + w * omw * dz * dz;
        oc.w = cv.w * omw + var.w * w + w * omw * dw * dw;
        om.x = m.x * omw + ave.x * w;
        om.y = m.y * omw + ave.y * w;
        om.z = m.z * omw + ave.z * w;
        om.w = m.w * omw + ave.w * w;
        *reinterpret_cast<float4*>(out + idx)       = oc;
        *reinterpret_cast<float4*>(out + CA_ + idx) = om;
        if (ct == 0) out[2 * CA_ + c] = amt + cntf;
    }
}

extern "C" void kernel_launch(void* const* d_in, const int* in_sizes, int n_in,
                              void* d_out, int out_size, void* d_ws, size_t ws_size,
                              hipStream_t stream)
{
    const float* feat   = (const float*)d_in[0];
    const int*   labels = (const int*)  d_in[1];
    const float* cov    = (const float*)d_in[2];
    const float* mean   = (const float*)d_in[3];
    const float* amount = (const float*)d_in[4];
    float* out = (float*)d_out;

    fused_kernel<<<C_, TPB, 0, stream>>>(feat, labels, cov, mean, amount, out);
}